// Round 7
// baseline (260.710 us; speedup 1.0000x reference)
//
#include <hip/hip_runtime.h>
#include <math.h>

// z = (64,64,64,64) fp32 -> 262144 vectors of dim 64; codebook = 1024 x 64 fp32.
constexpr int DIM  = 64;
constexpr int KCB  = 1024;
constexpr int NVEC = 262144;
constexpr long long NELEM = 16777216LL;
constexpr int TILES = 2;               // 32 rows/wave, 128 rows/block
constexpr int GRID  = NVEC / 128;      // 2048 blocks
constexpr int CCH   = 64;              // codewords per staged LDS chunk (8 KB)
constexpr int NCH   = KCB / CCH;       // 16 chunks

typedef short bf16x8 __attribute__((ext_vector_type(8)));  // 8 bf16 = 4 VGPRs
typedef float f32x4  __attribute__((ext_vector_type(4)));

// async global->LDS, 16 B per lane; LDS dest = wave-uniform base + lane*16
#define GLDS16(gp, lp) __builtin_amdgcn_global_load_lds(                      \
    (const __attribute__((address_space(1))) unsigned int*)(gp),              \
    (__attribute__((address_space(3))) unsigned int*)(lp), 16, 0, 0)

// fp32 -> bf16 round-to-nearest-even
__device__ __forceinline__ short f2bf(float f) {
    union { float f; unsigned u; } v; v.f = f;
    unsigned r = (v.u + 0x7fffu + ((v.u >> 16) & 1u)) >> 16;
    return (short)r;
}

// Prep: cbbf = bf16(-2*cb) row-major (col*64+k), esq = ||e_k||^2, zero ws[0..1].
__global__ __launch_bounds__(256) void vq_prep(const float* __restrict__ cb,
        short* __restrict__ cbbf, float* __restrict__ esq, float* __restrict__ ws) {
    int i = blockIdx.x * 256 + threadIdx.x;   // 256 blocks x 256 = 65536
    cbbf[i] = f2bf(-2.0f * cb[i]);
    if (i < KCB) {
        const float* e = cb + i * DIM;
        float s0 = 0.f, s1 = 0.f, s2 = 0.f, s3 = 0.f;
        #pragma unroll
        for (int j = 0; j < DIM; j += 4) {
            float4 v = *(const float4*)(e + j);
            s0 = fmaf(v.x, v.x, s0);
            s1 = fmaf(v.y, v.y, s1);
            s2 = fmaf(v.z, v.z, s2);
            s3 = fmaf(v.w, v.w, s3);
        }
        esq[i] = (s0 + s1) + (s2 + s3);
    }
    if (i == 0) { ws[0] = 0.f; ((unsigned*)ws)[1] = 0u; }
}

// Main. Occupancy-first layout: ~17 KB LDS + <=64 VGPR -> 8 blocks/CU, so
// barrier/vmcnt drains of one block hide behind 7 others. B staged via
// global_load_lds w16 with source-side XOR swizzle (unit `part` of codeword
// `col` at LDS slot col*8 + ((part+col)&7)); fragment ds_read_b128 at <=2-way
// conflict. esq read straight from global (L1-hot, 16 consecutive floats/wave).
__global__ __launch_bounds__(256, 8) void vq_main(
        const float* __restrict__ z,
        const float* __restrict__ cb,
        const short* __restrict__ cbbf,
        const float* __restrict__ esq,
        float* __restrict__ out,
        float* __restrict__ ws) {
    __shared__ unsigned sB[2][CCH * 32];   // 2 x 8 KB staged B
    __shared__ int      lds_idx[128];      // 4 waves x 32 rows

    const int tid  = threadIdx.x;
    const int lane = tid & 63;
    const int wave = tid >> 6;
    const int quad = lane >> 4;
    const int lrow = lane & 15;
    const int r0   = (blockIdx.x * 4 + wave) * (TILES * 16);

    // Staging geometry: chunk = 512 uint4 units; slot s = wave*128 + j*64 + lane
    // (j=0..1). Unit landing at slot s: col=s>>3, pos=s&7, part=(pos-col)&7.
    unsigned gofs[2], lofs[2];
    #pragma unroll
    for (int j = 0; j < 2; ++j) {
        int s = wave * 128 + j * 64 + lane;
        int col = s >> 3, pos = s & 7;
        gofs[j] = (unsigned)((col * 8 + ((pos - col) & 7)) * 16);
        lofs[j] = (unsigned)((wave * 128 + j * 64) * 16);
    }

    // A fragments: A[m=lane&15][k=quad*8+j], two K=32 halves, value = bf16(z).
    bf16x8 a0[TILES], a1[TILES];
    #pragma unroll
    for (int t = 0; t < TILES; ++t) {
        const float* zr = z + (size_t)(r0 + t * 16 + lrow) * DIM + quad * 8;
        float4 p0 = *(const float4*)(zr);
        float4 p1 = *(const float4*)(zr + 4);
        float4 p2 = *(const float4*)(zr + 32);
        float4 p3 = *(const float4*)(zr + 36);
        a0[t][0] = f2bf(p0.x); a0[t][1] = f2bf(p0.y);
        a0[t][2] = f2bf(p0.z); a0[t][3] = f2bf(p0.w);
        a0[t][4] = f2bf(p1.x); a0[t][5] = f2bf(p1.y);
        a0[t][6] = f2bf(p1.z); a0[t][7] = f2bf(p1.w);
        a1[t][0] = f2bf(p2.x); a1[t][1] = f2bf(p2.y);
        a1[t][2] = f2bf(p2.z); a1[t][3] = f2bf(p2.w);
        a1[t][4] = f2bf(p3.x); a1[t][5] = f2bf(p3.y);
        a1[t][6] = f2bf(p3.z); a1[t][7] = f2bf(p3.w);
    }

    // Stage chunk 0 (async; first __syncthreads drains vmcnt).
    const char* gB = (const char*)cbbf;
    #pragma unroll
    for (int j = 0; j < 2; ++j)
        GLDS16(gB + gofs[j], (char*)sB[0] + lofs[j]);
    __syncthreads();

    float best[TILES][4];
    #pragma unroll
    for (int t = 0; t < TILES; ++t)
        #pragma unroll
        for (int i = 0; i < 4; ++i) best[t][i] = INFINITY;

    const int pos0 = ((quad + lrow) & 7) * 4;       // b0: part=quad
    const int pos1 = ((quad + 4 + lrow) & 7) * 4;   // b1: part=quad+4

    for (int o = 0; o < NCH; ++o) {
        if (o < NCH - 1) {                           // async prefetch next chunk
            const char* src = gB + (o + 1) * (CCH * DIM * 2);
            #pragma unroll
            for (int j = 0; j < 2; ++j)
                GLDS16(src + gofs[j], (char*)sB[(o + 1) & 1] + lofs[j]);
        }
        const unsigned* buf = sB[o & 1];
        #pragma unroll
        for (int s = 0; s < 4; ++s) {
            const int row = s * 16 + lrow;
            bf16x8 b0 = *(const bf16x8*)&buf[row * 32 + pos0];
            bf16x8 b1 = *(const bf16x8*)&buf[row * 32 + pos1];
            const int col = o * CCH + row;
            const float es = esq[col];               // L1-hot broadcast line
            const unsigned colv = (unsigned)col;
            #pragma unroll
            for (int t = 0; t < TILES; ++t) {
                f32x4 acc = { es, es, es, es };  // C col = lane&15 -> ||e||^2 bcast
                acc = __builtin_amdgcn_mfma_f32_16x16x32_bf16(a0[t], b0, acc, 0, 0, 0);
                acc = __builtin_amdgcn_mfma_f32_16x16x32_bf16(a1[t], b1, acc, 0, 0, 0);
                #pragma unroll
                for (int i = 0; i < 4; ++i) {
                    unsigned u = __float_as_uint(acc[i]);
                    float pk = __uint_as_float((u & 0xFFFFFC00u) | colv);
                    best[t][i] = fminf(best[t][i], pk);
                }
            }
        }
        __syncthreads();   // drains prefetch vmcnt + fences buffer reuse
    }

    // fminf butterfly over 16-lane col group; row of (t,i) = t*16 + quad*4 + i.
    #pragma unroll
    for (int t = 0; t < TILES; ++t)
        #pragma unroll
        for (int i = 0; i < 4; ++i) {
            float bs = best[t][i];
            #pragma unroll
            for (int m = 1; m < 16; m <<= 1)
                bs = fminf(bs, __shfl_xor(bs, m, 64));
            if (lrow == 0)
                lds_idx[wave * 32 + t * 16 + quad * 4 + i] =
                    (int)(__float_as_uint(bs) & 0x3FFu);
        }
    __syncthreads();

    // Epilogue: gather exact fp32 codebook row, write out, exact fp32 loss.
    float lsum = 0.f;
    #pragma unroll 4
    for (int rr = 0; rr < 32; ++rr) {
        const int idx = lds_idx[wave * 32 + rr];
        const int row = r0 + rr;
        float e = cb[(size_t)idx * DIM + lane];
        float x = z[(size_t)row * DIM + lane];
        out[(size_t)row * DIM + lane] = e;
        float d = e - x;
        lsum = fmaf(d, d, lsum);
    }
    #pragma unroll
    for (int off = 32; off > 0; off >>= 1)
        lsum += __shfl_down(lsum, off, 64);
    if (lane == 0) atomicAdd(ws, lsum);

    __syncthreads();
    if (tid == 0) {
        unsigned old = atomicAdd((unsigned*)ws + 1, 1u);
        if (old == (unsigned)(GRID - 1)) {
            float s = atomicAdd(ws, 0.0f);   // coherent read of final sum
            out[NELEM] = 1.25f * s * (1.0f / (float)NELEM);
        }
    }
}

extern "C" void kernel_launch(void* const* d_in, const int* in_sizes, int n_in,
                              void* d_out, int out_size, void* d_ws, size_t ws_size,
                              hipStream_t stream) {
    const float* z  = (const float*)d_in[0];
    const float* cb = (const float*)d_in[1];
    float* out = (float*)d_out;

    float* ws   = (float*)d_ws;                           // [0]=loss, [1]=counter
    short* cbbf = (short*)((char*)d_ws + 512);            // 128 KB packed bf16(-2*cb)
    float* esq  = (float*)((char*)d_ws + 512 + 131072);   // 1024 fp32

    vq_prep<<<256, 256, 0, stream>>>(cb, cbbf, esq, ws);
    vq_main<<<GRID, 256, 0, stream>>>(z, cb, cbbf, esq, out, ws);
}